// Round 3
// baseline (176.843 us; speedup 1.0000x reference)
//
#include <hip/hip_runtime.h>

#define NB_CONV 256
#define NTHR 256

typedef float f4 __attribute__((ext_vector_type(4)));

// d_out layout: y[4096][64] followed by cache_new[4096][4][64][64]
__global__ __launch_bounds__(256)
void fmc_fused(const float* __restrict__ inputs,
               const float* __restrict__ cache,
               const float* __restrict__ wk,
               const float* __restrict__ bias,
               const int* __restrict__ idxp,
               float* __restrict__ y_out,
               float* __restrict__ cache_out,
               int nb_copy)
{
    const int idx = idxp[0];
    int iw = idx % 64;        if (iw < 0)  iw += 64;
    int iwi = (idx - 1) % 64; if (iwi < 0) iwi += 64;
    const bool upd = (idx - 1) >= 0;   // EXCLUSIVE=True
    const int tid = threadIdx.x;

    if (blockIdx.x < NB_CONV) {
        // ---------------- conv part: y[b][fo] for 16 batch rows ----------------
        // LDS = 16384 + 4096 = 20480 B exactly -> LDS allows 8 blocks/CU
        __shared__ float Ws[64][64];   // [ci][fo]; reads 2-way aliased (free, m136)
        __shared__ float Xs[64][16];   // [ci][b];  reads broadcast/conflict-free
        const int bbase = blockIdx.x * 16;
        const int fog = tid & 15;      // fo group: fo = 4*fog
        const int bp  = tid >> 4;      // compute threads: bp<8 -> b pair

        float acc[2][4];
        if (tid < 128) {
            const f4 bv = *(const f4*)(bias + (fog << 2));
            acc[0][0]=bv.x; acc[0][1]=bv.y; acc[0][2]=bv.z; acc[0][3]=bv.w;
            acc[1][0]=bv.x; acc[1][1]=bv.y; acc[1][2]=bv.z; acc[1][3]=bv.w;
        }

        for (int kh = 0; kh < 4; ++kh) {
            for (int kw = 0; kw < 7; ++kw) {
                if (kh == 3 && kw >= 3) break;          // autoregressive mask
                const int col = iw - 3 + kw;            // window col -> cache col
                int kind;                                // 0 zero, 1 inputs, 2 cache
                int hs = kh;
                if (col < 0 || col >= 64) kind = 0;
                else if (!upd) kind = 2;
                else if (iw != 0) kind = (kh == 3 && col == iwi) ? 1 : 2;   // case A
                else if (iwi != 0) {                                        // case B: shift(add)
                    if (kh == 3) kind = 0;
                    else if (kh == 2 && col == iwi) kind = 1;
                    else { kind = 2; hs = kh + 1; }
                } else {                                                     // case C: add(shift)
                    if (kh == 3) kind = (col == 0) ? 1 : 0;
                    else { kind = 2; hs = kh + 1; }
                }

                __syncthreads();   // protect LDS from previous tap's readers
                // stage W tap: [ci][fo] 64x64 (contiguous 1KB per wave pass)
                const float* wt = wk + (kh * 7 + kw) * 4096;
                #pragma unroll
                for (int i = 0; i < 4; ++i) {
                    const int f4i = tid + (i << 8);
                    const int ci = f4i >> 4;
                    const int fo = (f4i & 15) << 2;
                    *(f4*)&Ws[ci][fo] = *(const f4*)(wt + ci * 64 + fo);
                }
                // stage X (transposed): Xs[ci][b]
                {
                    const int bl = tid >> 4;
                    const int c4 = (tid & 15) << 2;
                    f4 v = (f4)(0.f);
                    if (kind == 1)
                        v = *(const f4*)(inputs + (bbase + bl) * 64 + c4);
                    else if (kind == 2)
                        v = *(const f4*)(cache + ((((bbase + bl) << 2) + hs) * 64 + col) * 64 + c4);
                    Xs[c4 + 0][bl] = v.x;
                    Xs[c4 + 1][bl] = v.y;
                    Xs[c4 + 2][bl] = v.z;
                    Xs[c4 + 3][bl] = v.w;
                }
                __syncthreads();

                if (tid < 128) {
                    #pragma unroll 8
                    for (int ci = 0; ci < 64; ++ci) {
                        const f4 w = *(const f4*)&Ws[ci][fog << 2];
                        const float2 x = *(const float2*)&Xs[ci][bp << 1];
                        acc[0][0] = fmaf(x.x, w.x, acc[0][0]);
                        acc[0][1] = fmaf(x.x, w.y, acc[0][1]);
                        acc[0][2] = fmaf(x.x, w.z, acc[0][2]);
                        acc[0][3] = fmaf(x.x, w.w, acc[0][3]);
                        acc[1][0] = fmaf(x.y, w.x, acc[1][0]);
                        acc[1][1] = fmaf(x.y, w.y, acc[1][1]);
                        acc[1][2] = fmaf(x.y, w.z, acc[1][2]);
                        acc[1][3] = fmaf(x.y, w.w, acc[1][3]);
                    }
                }
            }
        }
        if (tid < 128) {
            float* y0 = y_out + (bbase + (bp << 1)) * 64 + (fog << 2);
            *(f4*)y0        = (f4){acc[0][0], acc[0][1], acc[0][2], acc[0][3]};
            *(f4*)(y0 + 64) = (f4){acc[1][0], acc[1][1], acc[1][2], acc[1][3]};
        }
    } else {
        // ---------------- copy part: cache_new ----------------
        // stride is a multiple of 4096 (nb_copy = 256*(occ-1)), so each thread's
        // residue r = i & 4095 is LOOP-INVARIANT: hoist all case logic to a
        // per-thread (kind, src, step) and run a minimal load->store stream.
        const f4* __restrict__ c4 = (const f4*)cache;
        const f4* __restrict__ i4 = (const f4*)inputs;
        f4* __restrict__ o4 = (f4*)cache_out;
        const int t0 = (blockIdx.x - NB_CONV) * NTHR + tid;
        const int stride = nb_copy * NTHR;
        const int total = 4096 * 4096;   // float4 count; r-layout: b[12] h[2] w[6] e[4]

        const int r = t0 & 4095;
        const int h = r >> 10, w = (r >> 4) & 63, e = r & 15;

        int kind;            // 0 zero, 1 inputs, 2 cache
        int coff = 0;        // cache read offset (row shift)
        if (!upd)            kind = 2;
        else if (iw != 0)    kind = (h == 3 && w == iwi) ? 1 : 2;               // case A
        else if (iwi != 0) { kind = (h == 2 && w == iwi) ? 1 : (h < 3 ? 2 : 0); // case B
                             coff = 1024; }
        else               { kind = (h == 3) ? (w == 0 ? 1 : 0) : 2;            // case C
                             coff = 1024; }

        if (kind == 0) {
            for (int i = t0; i < total; i += stride)
                o4[i] = (f4)(0.f);
        } else {
            const f4* src;
            long sstep;
            if (kind == 1) { src = i4 + ((long)(t0 >> 12) << 4) + e;  // inputs[b][e*4..]
                             sstep = (long)(stride >> 12) << 4; }
            else           { src = c4 + t0 + coff;
                             sstep = stride; }
            for (int i = t0; i < total; i += stride) {
                o4[i] = *src;
                src += sstep;
            }
        }
    }
}

extern "C" void kernel_launch(void* const* d_in, const int* in_sizes, int n_in,
                              void* d_out, int out_size, void* d_ws, size_t ws_size,
                              hipStream_t stream) {
    const float* inputs = (const float*)d_in[0];
    const float* cache  = (const float*)d_in[1];
    const float* wk     = (const float*)d_in[2];
    const float* bias   = (const float*)d_in[3];
    const int*   idxp   = (const int*)d_in[4];
    float* y_out = (float*)d_out;
    float* cache_out = (float*)d_out + 4096 * 64;

    // Grid = 256 CUs * blocks/CU (deterministic host-side query; no stream ops).
    int occ = 0;
    if (hipOccupancyMaxActiveBlocksPerMultiprocessor(&occ,
            reinterpret_cast<const void*>(fmc_fused), NTHR, 0) != hipSuccess || occ < 2)
        occ = 7;
    const int nb_total = 256 * occ;
    const int nb_copy  = nb_total - NB_CONV;   // 256*(occ-1): stride % 4096 == 0

    fmc_fused<<<nb_total, NTHR, 0, stream>>>(inputs, cache, wk, bias, idxp,
                                             y_out, cache_out, nb_copy);
}

// Round 4
// 119.404 us; speedup vs baseline: 1.4810x; 1.4810x over previous
//
#include <hip/hip_runtime.h>

#define NB_CONV 256
#define NB_COPY 1536
#define NTHR 256

typedef float f4 __attribute__((ext_vector_type(4)));

// d_out layout: y[4096][64] followed by cache_new[4096][4][64][64]
__global__ __launch_bounds__(256)
void fmc_fused(const float* __restrict__ inputs,
               const float* __restrict__ cache,
               const float* __restrict__ wk,
               const float* __restrict__ bias,
               const int* __restrict__ idxp,
               float* __restrict__ y_out,
               float* __restrict__ cache_out)
{
    const int idx = idxp[0];
    int iw = idx % 64;        if (iw < 0)  iw += 64;
    int iwi = (idx - 1) % 64; if (iwi < 0) iwi += 64;
    const bool upd = (idx - 1) >= 0;   // EXCLUSIVE=True
    const int tid = threadIdx.x;

    if (blockIdx.x < NB_CONV) {
        // ---------------- conv part: y[b][fo] for 16 batch rows ----------------
        __shared__ float Ws[64][68];   // [ci][fo], padded (conflict-free staging)
        __shared__ float Xs[64][18];   // [ci][b],  padded
        const int bbase = blockIdx.x * 16;
        const int fog = tid & 15;      // fo group: fo = 4*fog
        const int bp  = tid >> 4;      // compute threads: bp<8 -> b pair

        float acc[2][4];
        if (tid < 128) {
            const f4 bv = *(const f4*)(bias + (fog << 2));
            acc[0][0]=bv.x; acc[0][1]=bv.y; acc[0][2]=bv.z; acc[0][3]=bv.w;
            acc[1][0]=bv.x; acc[1][1]=bv.y; acc[1][2]=bv.z; acc[1][3]=bv.w;
        }

        for (int kh = 0; kh < 4; ++kh) {
            for (int kw = 0; kw < 7; ++kw) {
                if (kh == 3 && kw >= 3) break;          // autoregressive mask
                const int col = iw - 3 + kw;            // window col -> cache col
                int kind;                                // 0 zero, 1 inputs, 2 cache
                int hs = kh;
                if (col < 0 || col >= 64) kind = 0;
                else if (!upd) kind = 2;
                else if (iw != 0) kind = (kh == 3 && col == iwi) ? 1 : 2;   // case A
                else if (iwi != 0) {                                        // case B: shift(add)
                    if (kh == 3) kind = 0;
                    else if (kh == 2 && col == iwi) kind = 1;
                    else { kind = 2; hs = kh + 1; }
                } else {                                                     // case C: add(shift)
                    if (kh == 3) kind = (col == 0) ? 1 : 0;
                    else { kind = 2; hs = kh + 1; }
                }

                __syncthreads();   // protect LDS from previous tap's readers
                // stage W tap: [ci][fo] 64x64
                const float* wt = wk + (kh * 7 + kw) * 4096;
                #pragma unroll
                for (int i = 0; i < 4; ++i) {
                    const int f4i = tid + (i << 8);
                    const int ci = f4i >> 4;
                    const int fo = (f4i & 15) << 2;
                    *(f4*)&Ws[ci][fo] = *(const f4*)(wt + ci * 64 + fo);
                }
                // stage X (transposed): Xs[ci][b]
                {
                    const int bl = tid >> 4;
                    const int c4 = (tid & 15) << 2;
                    f4 v = (f4)(0.f);
                    if (kind == 1)
                        v = *(const f4*)(inputs + (bbase + bl) * 64 + c4);
                    else if (kind == 2)
                        v = *(const f4*)(cache + ((((bbase + bl) << 2) + hs) * 64 + col) * 64 + c4);
                    Xs[c4 + 0][bl] = v.x;
                    Xs[c4 + 1][bl] = v.y;
                    Xs[c4 + 2][bl] = v.z;
                    Xs[c4 + 3][bl] = v.w;
                }
                __syncthreads();

                if (tid < 128) {
                    #pragma unroll 8
                    for (int ci = 0; ci < 64; ++ci) {
                        const f4 w = *(const f4*)&Ws[ci][fog << 2];
                        const float2 x = *(const float2*)&Xs[ci][bp << 1];
                        acc[0][0] = fmaf(x.x, w.x, acc[0][0]);
                        acc[0][1] = fmaf(x.x, w.y, acc[0][1]);
                        acc[0][2] = fmaf(x.x, w.z, acc[0][2]);
                        acc[0][3] = fmaf(x.x, w.w, acc[0][3]);
                        acc[1][0] = fmaf(x.y, w.x, acc[1][0]);
                        acc[1][1] = fmaf(x.y, w.y, acc[1][1]);
                        acc[1][2] = fmaf(x.y, w.z, acc[1][2]);
                        acc[1][3] = fmaf(x.y, w.w, acc[1][3]);
                    }
                }
            }
        }
        if (tid < 128) {
            float* y0 = y_out + (bbase + (bp << 1)) * 64 + (fog << 2);
            *(f4*)y0        = (f4){acc[0][0], acc[0][1], acc[0][2], acc[0][3]};
            *(f4*)(y0 + 64) = (f4){acc[1][0], acc[1][1], acc[1][2], acc[1][3]};
        }
    } else {
        // ---------------- copy part: cache_new ----------------
        // stride = 1536*256 = 96*4096, so r = i & 4095 is LOOP-INVARIANT:
        // hoist all case logic; body = 4 independent loads -> 4 stores.
        const f4* __restrict__ c4 = (const f4*)cache;
        const f4* __restrict__ i4 = (const f4*)inputs;
        f4* __restrict__ o4 = (f4*)cache_out;
        const int t0 = (blockIdx.x - NB_CONV) * NTHR + tid;
        const int stride = NB_COPY * NTHR;
        const int total = 4096 * 4096;   // float4 count; r-layout: b[12] h[2] w[6] e[4]

        const int r = t0 & 4095;
        const int h = r >> 10, w = (r >> 4) & 63, e = r & 15;

        int kind;            // 0 zero, 1 inputs, 2 cache
        int coff = 0;        // cache read offset (row shift)
        if (!upd)            kind = 2;
        else if (iw != 0)    kind = (h == 3 && w == iwi) ? 1 : 2;               // case A
        else if (iwi != 0) { kind = (h == 2 && w == iwi) ? 1 : (h < 3 ? 2 : 0); // case B
                             coff = 1024; }
        else               { kind = (h == 3) ? (w == 0 ? 1 : 0) : 2;            // case C
                             coff = 1024; }

        if (kind == 2) {
            int i = t0;
            for (; i + 3 * stride < total; i += 4 * stride) {
                const f4 v0 = c4[i              + coff];
                const f4 v1 = c4[i +     stride + coff];
                const f4 v2 = c4[i + 2 * stride + coff];
                const f4 v3 = c4[i + 3 * stride + coff];
                o4[i]              = v0;
                o4[i +     stride] = v1;
                o4[i + 2 * stride] = v2;
                o4[i + 3 * stride] = v3;
            }
            for (; i < total; i += stride)
                o4[i] = c4[i + coff];
        } else if (kind == 1) {          // rare: 16/4096 residues
            for (int i = t0; i < total; i += stride)
                o4[i] = i4[((i >> 12) << 4) + e];
        } else {                          // zero-fill
            const f4 z = (f4)(0.f);
            int i = t0;
            for (; i + 3 * stride < total; i += 4 * stride) {
                o4[i]              = z;
                o4[i +     stride] = z;
                o4[i + 2 * stride] = z;
                o4[i + 3 * stride] = z;
            }
            for (; i < total; i += stride)
                o4[i] = z;
        }
    }
}

extern "C" void kernel_launch(void* const* d_in, const int* in_sizes, int n_in,
                              void* d_out, int out_size, void* d_ws, size_t ws_size,
                              hipStream_t stream) {
    const float* inputs = (const float*)d_in[0];
    const float* cache  = (const float*)d_in[1];
    const float* wk     = (const float*)d_in[2];
    const float* bias   = (const float*)d_in[3];
    const int*   idxp   = (const int*)d_in[4];
    float* y_out = (float*)d_out;
    float* cache_out = (float*)d_out + 4096 * 64;
    fmc_fused<<<NB_CONV + NB_COPY, NTHR, 0, stream>>>(inputs, cache, wk, bias, idxp,
                                                      y_out, cache_out);
}